// Round 1
// 770.597 us; speedup vs baseline: 1.0267x; 1.0267x over previous
//
#include <hip/hip_runtime.h>
#include <stdint.h>

#define S_LEN 2048
#define EMB   4096
#define NHEAD 32
#define DHEAD 128
#define NBLK  32
#define GDIM  64

typedef float  f32x4  __attribute__((ext_vector_type(4)));
typedef __bf16 bf16x8 __attribute__((ext_vector_type(8)));
typedef unsigned short u16;

__device__ __forceinline__ u16 f2bf(float f) {
  uint32_t u = __float_as_uint(f);
  u += 0x7fffu + ((u >> 16) & 1u);
  return (u16)(u >> 16);
}
__device__ __forceinline__ float bf2f(u16 u) {
  return __uint_as_float(((uint32_t)u) << 16);
}

__device__ __forceinline__ void ld_lds16(const u16* g, u16* l) {
  __builtin_amdgcn_global_load_lds((const __attribute__((address_space(1))) void*)g,
                                   (__attribute__((address_space(3))) void*)l, 16, 0, 0);
}

// fp32 -> bf16 bulk convert (vectorized, n4 = n/4)
__global__ void conv_f32_bf16(const float* __restrict__ in, u16* __restrict__ out, int n4) {
  int i = blockIdx.x * 256 + threadIdx.x;
  if (i >= n4) return;
  float4 v = ((const float4*)in)[i];
  ushort4 o;
  o.x = f2bf(v.x); o.y = f2bf(v.y); o.z = f2bf(v.z); o.w = f2bf(v.w);
  ((ushort4*)out)[i] = o;
}

// three weights in one dispatch (grid.y selects)
__global__ void conv3_f32_bf16(const float* __restrict__ a, const float* __restrict__ b,
                               const float* __restrict__ c, u16* __restrict__ oa,
                               u16* __restrict__ ob, u16* __restrict__ oc, int n4) {
  int i = blockIdx.x * 256 + threadIdx.x;
  if (i >= n4) return;
  const float* in = (blockIdx.y == 0) ? a : (blockIdx.y == 1) ? b : c;
  u16* out = (blockIdx.y == 0) ? oa : (blockIdx.y == 1) ? ob : oc;
  float4 v = ((const float4*)in)[i];
  ushort4 o;
  o.x = f2bf(v.x); o.y = f2bf(v.y); o.z = f2bf(v.z); o.w = f2bf(v.w);
  ((ushort4*)out)[i] = o;
}

// ---------------------------------------------------------------------------
// Fused QKV projection, 256x256 tile / BK=32 / 4-deep LDS ring / counted vmcnt.
// grid (48, 8): blockIdx.x>>4 selects weight (0=Q RoPE, 1=K RoPE, 2=V transpose),
// blockIdx.x&15 = n-tile (2 heads), blockIdx.y = m-tile.
// 512 threads = 8 waves as 2M x 4N; wave tile 128x64 (8x4 frags).
// LDS (dynamic, 128 KiB): A ring 4 x 256x32 bf16, B ring 4 x 256x32 bf16.
// XOR slot swizzle: stored slot = logical_slot ^ ((row>>1)&3) (16B slots, 64B rows)
//   -> ds_read_b128 is 2-way (free); applied inversely on the global source of
//   global_load_lds (linear LDS dest).
// K-loop: per tile, one s_waitcnt vmcnt(8)+lgkmcnt(0) + raw s_barrier (loads for
// tiles t+1,t+2 stay in flight across the barrier), two 16-MFMA phases with
// setprio(1), staging of tile t+3 interleaved. Tail drains vmcnt 8->4->0.
// ---------------------------------------------------------------------------
__global__ void __launch_bounds__(512, 2) qkv_gemm_256(
    const u16* __restrict__ A, const u16* __restrict__ Bq, const u16* __restrict__ Bk,
    const u16* __restrict__ Bv, u16* __restrict__ outq, u16* __restrict__ outk,
    u16* __restrict__ outvt, const float* __restrict__ cosp, const float* __restrict__ sinp)
{
  extern __shared__ u16 lds[];   // 65536 u16 = 128 KiB; A: [0,32768) B: [32768,65536)

  const int tid  = threadIdx.x;
  const int w    = tid >> 6;          // wave 0..7
  const int lane = tid & 63;
  const int r    = lane & 15;         // row-in-frag
  const int qd   = lane >> 4;         // k-slot
  const int wr   = w >> 2;            // wave M half 0..1
  const int wc   = w & 3;             // wave N strip 0..3

  const int which = blockIdx.x >> 4;  // 0=Q 1=K 2=V
  const int nt    = blockIdx.x & 15;  // n-tile (2 heads)
  const int m0    = blockIdx.y * 256;
  const int n0    = nt * 256;
  const int K     = EMB;
  const u16* B = (which == 0) ? Bq : (which == 1) ? Bk : Bv;

  // N-frag columns, RoPE-pair-local: {lo, lo+16, lo+64, lo+80} within a head
  const int cb0 = (wc >> 1) * 128 + (wc & 1) * 32;
  const int cb1 = cb0 + 16;
  const int cb2 = cb0 + 64;
  const int cb3 = cb0 + 80;

  // swizzled read offset within a [256][32] buffer (u16 elements)
  const int fragoff = r * 32 + ((qd ^ ((r >> 1) & 3)) << 3);

  // staging global bases: row = j*128 + w*16 + (lane>>2), slot = (lane&3)^((lane>>3)&3)
  const int srow_st = w * 16 + (lane >> 2);
  const int sslot   = ((lane & 3) ^ ((lane >> 3) & 3)) * 8;
  const u16* Ab0 = A + (size_t)(m0 + srow_st) * K + sslot;
  const u16* Ab1 = Ab0 + (size_t)128 * K;
  const u16* Bb0 = B + (size_t)(n0 + srow_st) * K + sslot;
  const u16* Bb1 = Bb0 + (size_t)128 * K;

  f32x4 acc[8][4];
#pragma unroll
  for (int mi = 0; mi < 8; ++mi)
#pragma unroll
    for (int ni = 0; ni < 4; ++ni) acc[mi][ni] = (f32x4){0.f, 0.f, 0.f, 0.f};

  auto stageA = [&](int tt) {
    u16* d = lds + (tt & 3) * 8192 + w * 512;
    const int kk = tt * 32;
    ld_lds16(Ab0 + kk, d);
    ld_lds16(Ab1 + kk, d + 4096);
  };
  auto stageB = [&](int tt) {
    u16* d = lds + 32768 + (tt & 3) * 8192 + w * 512;
    const int kk = tt * 32;
    ld_lds16(Bb0 + kk, d);
    ld_lds16(Bb1 + kk, d + 4096);
  };

  // prologue: 3 tiles in flight
  stageA(0); stageB(0);
  stageA(1); stageB(1);
  stageA(2); stageB(2);

  for (int t = 0; t < 128; ++t) {
    const int buf = t & 3;
    // tile t must be resident; keep t+1,t+2 (8 loads/wave) in flight.
    if (t < 126)       asm volatile("s_waitcnt vmcnt(8) lgkmcnt(0)" ::: "memory");
    else if (t == 126) asm volatile("s_waitcnt vmcnt(4) lgkmcnt(0)" ::: "memory");
    else               asm volatile("s_waitcnt vmcnt(0) lgkmcnt(0)" ::: "memory");
    __builtin_amdgcn_sched_barrier(0);
    __builtin_amdgcn_s_barrier();

    const u16* lAb = lds + buf * 8192 + wr * 128 * 32;
    const u16* lBb = lds + 32768 + buf * 8192;

    bf16x8 bfr[4];
    bfr[0] = *(const bf16x8*)(lBb + cb0 * 32 + fragoff);
    bfr[1] = *(const bf16x8*)(lBb + cb1 * 32 + fragoff);
    bfr[2] = *(const bf16x8*)(lBb + cb2 * 32 + fragoff);
    bfr[3] = *(const bf16x8*)(lBb + cb3 * 32 + fragoff);

    bf16x8 af[4];
#pragma unroll
    for (int mi = 0; mi < 4; ++mi) af[mi] = *(const bf16x8*)(lAb + mi * 512 + fragoff);
    if (t < 125) stageA(t + 3);

    __builtin_amdgcn_s_setprio(1);
#pragma unroll
    for (int mi = 0; mi < 4; ++mi)
#pragma unroll
      for (int ni = 0; ni < 4; ++ni)
        acc[mi][ni] = __builtin_amdgcn_mfma_f32_16x16x32_bf16(af[mi], bfr[ni], acc[mi][ni], 0, 0, 0);
    __builtin_amdgcn_s_setprio(0);

    bf16x8 af2[4];
#pragma unroll
    for (int mi = 0; mi < 4; ++mi) af2[mi] = *(const bf16x8*)(lAb + (mi + 4) * 512 + fragoff);
    if (t < 125) stageB(t + 3);

    __builtin_amdgcn_s_setprio(1);
#pragma unroll
    for (int mi = 0; mi < 4; ++mi)
#pragma unroll
      for (int ni = 0; ni < 4; ++ni)
        acc[mi + 4][ni] = __builtin_amdgcn_mfma_f32_16x16x32_bf16(af2[mi], bfr[ni], acc[mi + 4][ni], 0, 0, 0);
    __builtin_amdgcn_s_setprio(0);
  }

  if (which < 2) {
    // RoPE epilogue; pairs (d, d+64) are wave-local: lo = ni{0,1}, hi = ni{2,3}
    u16* out = which ? outk : outq;
    const int hh = 2 * nt + (wc >> 1);
    const int dbase = (wc & 1) * 32;
#pragma unroll
    for (int mi = 0; mi < 8; ++mi)
#pragma unroll
      for (int ni = 0; ni < 2; ++ni) {
        const int dlo = dbase + ni * 16 + r;
#pragma unroll
        for (int rg = 0; rg < 4; ++rg) {
          int srow = m0 + wr * 128 + mi * 16 + qd * 4 + rg;
          float c = cosp[srow * DHEAD + dlo];
          float s = sinp[srow * DHEAD + dlo];
          float lo = acc[mi][ni][rg], hi = acc[mi][ni + 2][rg];
          size_t base = ((size_t)hh * S_LEN + srow) * DHEAD;
          out[base + dlo]      = f2bf(lo * c - hi * s);
          out[base + dlo + 64] = f2bf(hi * c + lo * s);
        }
      }
  } else {
    // V: transpose 256x256 tile through LDS (reused) in two 128-row chunks -> (H, D, S)
    u16* lT = lds;  // [256 cols][136]
#pragma unroll
    for (int ch = 0; ch < 2; ++ch) {
      __syncthreads();
      if (wr == ch) {
#pragma unroll
        for (int mi = 0; mi < 8; ++mi) {
          const int lr = mi * 16 + qd * 4;
          const int cbs[4] = {cb0, cb1, cb2, cb3};
#pragma unroll
          for (int ni = 0; ni < 4; ++ni) {
            const int col = cbs[ni] + r;
#pragma unroll
            for (int rg = 0; rg < 4; ++rg)
              lT[col * 136 + lr + rg] = f2bf(acc[mi][ni][rg]);
          }
        }
      }
      __syncthreads();
      const int c = tid >> 1, sh = (tid & 1) * 64;
      const int hh2 = 2 * nt + (c >> 7), d = c & 127;
      size_t obase = ((size_t)hh2 * DHEAD + d) * S_LEN + m0 + ch * 128 + sh;
#pragma unroll
      for (int i8 = 0; i8 < 8; ++i8) {
        uint4 v = *(const uint4*)&lT[c * 136 + sh + i8 * 8];
        *(uint4*)&outvt[obase + i8 * 8] = v;
      }
    }
  }
}

// Output projection: C(2048x4096) = ctx @ Wo^T, f32 out.
__global__ void __launch_bounds__(256, 2) gemm_out(
    const u16* __restrict__ A, const u16* __restrict__ B, float* __restrict__ out)
{
  __shared__ u16 lA[128 * 32];
  __shared__ u16 lB[128 * 32];
  const int tid = threadIdx.x;
  const int w = tid >> 6, lane = tid & 63;
  const int r = lane & 15, qd = lane >> 4;
  const int m0 = blockIdx.y * 128, n0 = blockIdx.x * 128;
  const int K = EMB;

  f32x4 acc[2][8];
#pragma unroll
  for (int mi = 0; mi < 2; ++mi)
#pragma unroll
    for (int ni = 0; ni < 8; ++ni) acc[mi][ni] = (f32x4){0.f, 0.f, 0.f, 0.f};

  const u16* Ab = A + (size_t)(m0 + w * 16 + (lane >> 2)) * K + (lane & 3) * 8;
  const u16* Bb = B + (size_t)(n0 + w * 16 + (lane >> 2)) * K + (lane & 3) * 8;
  u16* lAb = &lA[(w * 16) * 32];
  u16* lBb = &lB[(w * 16) * 32];

  for (int k0 = 0; k0 < K; k0 += 32) {
    __syncthreads();
    ld_lds16(Ab + k0, lAb);
    ld_lds16(Ab + (size_t)64 * K + k0, lAb + 64 * 32);
    ld_lds16(Bb + k0, lBb);
    ld_lds16(Bb + (size_t)64 * K + k0, lBb + 64 * 32);
    __syncthreads();
    bf16x8 af0 = *(const bf16x8*)&lA[(w * 32 + r) * 32 + qd * 8];
    bf16x8 af1 = *(const bf16x8*)&lA[(w * 32 + 16 + r) * 32 + qd * 8];
#pragma unroll
    for (int ni = 0; ni < 8; ++ni) {
      bf16x8 bf = *(const bf16x8*)&lB[(ni * 16 + r) * 32 + qd * 8];
      acc[0][ni] = __builtin_amdgcn_mfma_f32_16x16x32_bf16(af0, bf, acc[0][ni], 0, 0, 0);
      acc[1][ni] = __builtin_amdgcn_mfma_f32_16x16x32_bf16(af1, bf, acc[1][ni], 0, 0, 0);
    }
  }
#pragma unroll
  for (int mi = 0; mi < 2; ++mi)
#pragma unroll
    for (int ni = 0; ni < 8; ++ni)
#pragma unroll
      for (int rg = 0; rg < 4; ++rg) {
        int srow = m0 + w * 32 + mi * 16 + qd * 4 + rg;
        out[(size_t)srow * EMB + n0 + ni * 16 + r] = acc[mi][ni][rg];
      }
}

// flash attention, load-balanced: block (blockIdx.x in [0,16)) processes q-blocks
// qb = blockIdx.x and 31-blockIdx.x  => exactly 33 K-tiles per block.
__global__ void __launch_bounds__(256, 2) attn_fwd(
    const u16* __restrict__ qg, const u16* __restrict__ kg, const u16* __restrict__ vtg,
    u16* __restrict__ ctx, float* __restrict__ bmax)
{
  __shared__ u16 lK[64 * 132];
  __shared__ u16 lV[128 * 76];
  __shared__ u16 lP[64 * 76];
  __shared__ float lBM[4 * NBLK];

  const int tid = threadIdx.x;
  const int w = tid >> 6, lane = tid & 63;
  const int r = lane & 15, qd = lane >> 4;
  const int h = blockIdx.y;
  const u16* ksrc = kg + (size_t)h * S_LEN * DHEAD;
  const u16* vsrc = vtg + (size_t)h * DHEAD * S_LEN;
  const float scale = 0.08838834764831845f;

  for (int qsel = 0; qsel < 2; ++qsel) {
    const int qb = qsel ? (31 - (int)blockIdx.x) : (int)blockIdx.x;

    bf16x8 qf[4];
    {
      const u16* qp = qg + ((size_t)h * S_LEN + qb * 64 + w * 16 + r) * DHEAD + qd * 8;
#pragma unroll
      for (int ki = 0; ki < 4; ++ki) qf[ki] = *(const bf16x8*)(qp + ki * 32);
    }

    f32x4 o[8];
#pragma unroll
    for (int dt = 0; dt < 8; ++dt) o[dt] = (f32x4){0.f, 0.f, 0.f, 0.f};
    float m_run[4], l_run[4];
#pragma unroll
    for (int rg = 0; rg < 4; ++rg) { m_run[rg] = -__builtin_inff(); l_run[rg] = 0.f; }

    for (int kb = 0; kb <= qb; ++kb) {
      __syncthreads();
#pragma unroll
      for (int i = 0; i < 4; ++i) {
        int c = tid + 256 * i;
        int row = c >> 4, col = (c & 15) * 8;
        *(uint4*)&lK[row * 132 + col] = *(const uint4*)(ksrc + (size_t)(kb * 64 + row) * DHEAD + col);
      }
#pragma unroll
      for (int i = 0; i < 4; ++i) {
        int c = tid + 256 * i;
        int row = c >> 3, col = (c & 7) * 8;
        *(uint4*)&lV[row * 76 + col] = *(const uint4*)(vsrc + (size_t)row * S_LEN + kb * 64 + col);
      }
      __syncthreads();

      f32x4 sf[4];
#pragma unroll
      for (int nt = 0; nt < 4; ++nt) sf[nt] = (f32x4){0.f, 0.f, 0.f, 0.f};
#pragma unroll
      for (int ki = 0; ki < 4; ++ki)
#pragma unroll
        for (int nt = 0; nt < 4; ++nt) {
          bf16x8 bf = *(const bf16x8*)&lK[(nt * 16 + r) * 132 + ki * 32 + qd * 8];
          sf[nt] = __builtin_amdgcn_mfma_f32_16x16x32_bf16(qf[ki], bf, sf[nt], 0, 0, 0);
        }

      float rmax[4];
#pragma unroll
      for (int rg = 0; rg < 4; ++rg) rmax[rg] = -__builtin_inff();
#pragma unroll
      for (int nt = 0; nt < 4; ++nt)
#pragma unroll
        for (int rg = 0; rg < 4; ++rg) {
          float s = sf[nt][rg] * scale;
          if (kb == qb) {
            int col = nt * 16 + r, row = w * 16 + qd * 4 + rg;
            if (col > row) s = -__builtin_inff();
          }
          sf[nt][rg] = s;
          rmax[rg] = fmaxf(rmax[rg], s);
        }
#pragma unroll
      for (int rg = 0; rg < 4; ++rg) {
        float v = rmax[rg];
        v = fmaxf(v, __shfl_xor(v, 1));
        v = fmaxf(v, __shfl_xor(v, 2));
        v = fmaxf(v, __shfl_xor(v, 4));
        v = fmaxf(v, __shfl_xor(v, 8));
        rmax[rg] = v;
      }
      {  // per-wave tile max -> lBM for gate_target block_max
        float v = fmaxf(fmaxf(rmax[0], rmax[1]), fmaxf(rmax[2], rmax[3]));
        v = fmaxf(v, __shfl_xor(v, 16));
        v = fmaxf(v, __shfl_xor(v, 32));
        if (lane == 0) lBM[w * NBLK + kb] = v;
      }

      float alpha[4], rsum[4];
#pragma unroll
      for (int rg = 0; rg < 4; ++rg) {
        float mn = fmaxf(m_run[rg], rmax[rg]);
        alpha[rg] = __expf(m_run[rg] - mn);
        m_run[rg] = mn;
        rsum[rg] = 0.f;
      }
#pragma unroll
      for (int nt = 0; nt < 4; ++nt)
#pragma unroll
        for (int rg = 0; rg < 4; ++rg) {
          float p = __expf(sf[nt][rg] - m_run[rg]);
          sf[nt][rg] = p;
          rsum[rg] += p;
        }
#pragma unroll
      for (int rg = 0; rg < 4; ++rg) {
        float v = rsum[rg];
        v += __shfl_xor(v, 1);
        v += __shfl_xor(v, 2);
        v += __shfl_xor(v, 4);
        v += __shfl_xor(v, 8);
        l_run[rg] = l_run[rg] * alpha[rg] + v;
      }
      // P (C-layout) -> LDS -> A-layout; each wave touches only its own 16 rows
#pragma unroll
      for (int nt = 0; nt < 4; ++nt)
#pragma unroll
        for (int rg = 0; rg < 4; ++rg)
          lP[(w * 16 + qd * 4 + rg) * 76 + nt * 16 + r] = f2bf(sf[nt][rg]);
#pragma unroll
      for (int dt = 0; dt < 8; ++dt)
#pragma unroll
        for (int rg = 0; rg < 4; ++rg) o[dt][rg] *= alpha[rg];
      bf16x8 pa0 = *(const bf16x8*)&lP[(w * 16 + r) * 76 + qd * 8];
      bf16x8 pa1 = *(const bf16x8*)&lP[(w * 16 + r) * 76 + 32 + qd * 8];
#pragma unroll
      for (int dt = 0; dt < 8; ++dt) {
        bf16x8 bv0 = *(const bf16x8*)&lV[(dt * 16 + r) * 76 + qd * 8];
        bf16x8 bv1 = *(const bf16x8*)&lV[(dt * 16 + r) * 76 + 32 + qd * 8];
        o[dt] = __builtin_amdgcn_mfma_f32_16x16x32_bf16(pa0, bv0, o[dt], 0, 0, 0);
        o[dt] = __builtin_amdgcn_mfma_f32_16x16x32_bf16(pa1, bv1, o[dt], 0, 0, 0);
      }
    }

    float inv[4];
#pragma unroll
    for (int rg = 0; rg < 4; ++rg) inv[rg] = 1.f / l_run[rg];
#pragma unroll
    for (int dt = 0; dt < 8; ++dt)
#pragma unroll
      for (int rg = 0; rg < 4; ++rg) {
        int srow = qb * 64 + w * 16 + qd * 4 + rg;
        ctx[(size_t)srow * EMB + h * DHEAD + dt * 16 + r] = f2bf(o[dt][rg] * inv[rg]);
      }
    __syncthreads();
    if (tid <= qb) {
      float v = fmaxf(fmaxf(lBM[0 * NBLK + tid], lBM[1 * NBLK + tid]),
                      fmaxf(lBM[2 * NBLK + tid], lBM[3 * NBLK + tid]));
      bmax[((size_t)h * NBLK + qb) * NBLK + tid] = v;
    }
  }
}

// per-(h,nb) mean over 64 rows, q and k in one dispatch (grid.z selects). 128 thr, u32 loads.
__global__ void bmean2(const u16* __restrict__ q, const u16* __restrict__ k,
                       float* __restrict__ qo, float* __restrict__ ko) {
  int nb = blockIdx.x, h = blockIdx.y, t = threadIdx.x;
  const u16* x = blockIdx.z ? k : q;
  float* out = blockIdx.z ? ko : qo;
  const u16* p = x + ((size_t)h * S_LEN + nb * 64) * DHEAD + t * 2;
  float s0 = 0.f, s1 = 0.f;
#pragma unroll 8
  for (int i = 0; i < 64; ++i) {
    uint32_t v = *(const uint32_t*)(p + (size_t)i * DHEAD);
    s0 += bf2f((u16)v);
    s1 += bf2f((u16)(v >> 16));
  }
  float2 rr = {s0 * (1.f / 64.f), s1 * (1.f / 64.f)};
  *(float2*)&out[((size_t)h * NBLK + nb) * DHEAD + t * 2] = rr;
}

// gate_pred + gate_target, one block per head
__global__ void __launch_bounds__(256) gate_kernel(
    const float* __restrict__ qm, const float* __restrict__ km,
    const float* __restrict__ Wgq, const float* __restrict__ Wgk,
    const float* __restrict__ bmx, float* __restrict__ gpred, float* __restrict__ gtgt)
{
  __shared__ float gq[NBLK * GDIM], gk[NBLK * GDIM];
  __shared__ float red[256];
  const int h = blockIdx.x, tid = threadIdx.x;

  for (int i = 0; i < 8; ++i) {
    int e = tid + 256 * i;
    int n = e >> 6, g = e & 63;
    const float* qrow = qm + ((size_t)h * NBLK + n) * DHEAD;
    const float* krow = km + ((size_t)h * NBLK + n) * DHEAD;
    const float* wq = Wgq + g * DHEAD;
    const float* wk = Wgk + g * DHEAD;
    float s1 = 0.f, s2 = 0.f;
    for (int d = 0; d < DHEAD; ++d) { s1 += qrow[d] * wq[d]; s2 += krow[d] * wk[d]; }
    gq[e] = s1; gk[e] = s2;
  }
  __syncthreads();

  float gl[4];
  for (int i = 0; i < 4; ++i) {
    int idx = tid + 256 * i;
    int qn = idx >> 5, kn = idx & 31;
    if (kn <= qn) {
      float s = 0.f;
      for (int g = 0; g < GDIM; ++g) s += gq[qn * GDIM + g] * gk[kn * GDIM + g];
      gl[i] = s * 0.125f;
    } else gl[i] = -__builtin_inff();
  }
  float mx = fmaxf(fmaxf(gl[0], gl[1]), fmaxf(gl[2], gl[3]));
  red[tid] = mx; __syncthreads();
  for (int st = 128; st > 0; st >>= 1) { if (tid < st) red[tid] = fmaxf(red[tid], red[tid + st]); __syncthreads(); }
  float gmax = red[0]; __syncthreads();
  float ex[4], lsum = 0.f;
  for (int i = 0; i < 4; ++i) { ex[i] = __expf(gl[i] - gmax); lsum += ex[i]; }
  red[tid] = lsum; __syncthreads();
  for (int st = 128; st > 0; st >>= 1) { if (tid < st) red[tid] += red[tid + st]; __syncthreads(); }
  float invs = 1.f / red[0]; __syncthreads();
  for (int i = 0; i < 4; ++i) gpred[(size_t)h * 1024 + tid + 256 * i] = ex[i] * invs;

  float tl[4];
  for (int i = 0; i < 4; ++i) {
    int idx = tid + 256 * i;
    int qn = idx >> 5, kn = idx & 31;
    tl[i] = (kn <= qn) ? fminf(fmaxf(bmx[(size_t)h * 1024 + idx], -50.f), 50.f) * 0.5f
                       : -__builtin_inff();
  }
  float mx2 = fmaxf(fmaxf(tl[0], tl[1]), fmaxf(tl[2], tl[3]));
  red[tid] = mx2; __syncthreads();
  for (int st = 128; st > 0; st >>= 1) { if (tid < st) red[tid] = fmaxf(red[tid], red[tid + st]); __syncthreads(); }
  float tmax = red[0]; __syncthreads();
  float ex2[4], ls2 = 0.f;
  for (int i = 0; i < 4; ++i) { ex2[i] = __expf(tl[i] - tmax); ls2 += ex2[i]; }
  red[tid] = ls2; __syncthreads();
  for (int st = 128; st > 0; st >>= 1) { if (tid < st) red[tid] += red[tid + st]; __syncthreads(); }
  float inv2 = 1.f / red[0];
  for (int i = 0; i < 4; ++i) gtgt[(size_t)h * 1024 + tid + 256 * i] = ex2[i] * inv2;
}

extern "C" void kernel_launch(void* const* d_in, const int* in_sizes, int n_in,
                              void* d_out, int out_size, void* d_ws, size_t ws_size,
                              hipStream_t stream) {
  const float* hidden = (const float*)d_in[0];
  const float* cosp   = (const float*)d_in[1];
  const float* sinp   = (const float*)d_in[2];
  const float* Wq     = (const float*)d_in[3];
  const float* Wk     = (const float*)d_in[4];
  const float* Wv     = (const float*)d_in[5];
  const float* Wo     = (const float*)d_in[6];
  const float* Wgq    = (const float*)d_in[7];
  const float* Wgk    = (const float*)d_in[8];

  char* ws = (char*)d_ws;
  // ws layout (total exactly 128 MiB):
  u16* wqb = (u16*)ws;                         // 33,554,432 B (Wq bf16; later Wo bf16)
  u16* wkb = (u16*)(ws + 33554432);            // 33,554,432 B (Wk bf16; later bmx/qmn/kmn)
  u16* hid = (u16*)(ws + 67108864);            // 16,777,216 B (hidden bf16; later ctx)
  u16* qbf = (u16*)(ws + 83886080);            // 16,777,216 B
  u16* kbf = (u16*)(ws + 100663296);           // 16,777,216 B
  u16* vtb = (u16*)(ws + 117440512);           // 16,777,216 B  -> end 134,217,728
  // aliases (regions free after qkv_gemm):
  float* bmx = (float*)(ws + 33554432);        // 131,072 B
  float* qmn = (float*)(ws + 33554432 + 131072);
  float* kmn = (float*)(ws + 33554432 + 655360);
  u16* ctx = hid;                              // hid dead after qkv_gemm
  u16* wvb = (u16*)d_out;                      // Wv bf16 staged in d_out scratch (33.5 MB);
                                               // overwritten by gemm_out at the end.

  float* attn_out = (float*)d_out;
  float* gpred = attn_out + (size_t)S_LEN * EMB;
  float* gtgt  = gpred + NHEAD * NBLK * NBLK;

  conv3_f32_bf16<<<dim3(16384, 3), 256, 0, stream>>>(Wq, Wk, Wv, wqb, wkb, wvb, 4194304);
  conv_f32_bf16<<<8192, 256, 0, stream>>>(hidden, hid, 2097152);

  static bool attr_set = false;
  if (!attr_set) {
    (void)hipFuncSetAttribute((const void*)qkv_gemm_256,
                              hipFuncAttributeMaxDynamicSharedMemorySize, 131072);
    attr_set = true;
  }
  qkv_gemm_256<<<dim3(48, 8), 512, 131072, stream>>>(hid, wqb, wkb, wvb, qbf, kbf, vtb, cosp, sinp);

  conv_f32_bf16<<<16384, 256, 0, stream>>>(Wo, wqb, 4194304);  // wqb free after qkv_gemm

  attn_fwd<<<dim3(16, NHEAD), 256, 0, stream>>>(qbf, kbf, vtb, ctx, bmx);

  bmean2<<<dim3(NBLK, NHEAD, 2), 128, 0, stream>>>(qbf, kbf, qmn, kmn);
  gate_kernel<<<NHEAD, 256, 0, stream>>>(qmn, kmn, Wgq, Wgk, bmx, gpred, gtgt);

  gemm_out<<<dim3(32, 16), 256, 0, stream>>>(ctx, wqb, attn_out);
}